// Round 1
// baseline (456.087 us; speedup 1.0000x reference)
//
#include <hip/hip_runtime.h>
#include <math.h>

#define NB 32
#define NN 512
#define DD 256

constexpr float F_EPS     = 0.1f;
constexpr float INV_EPS   = 10.0f;
constexpr float F_TINY    = 1e-16f;
constexpr float F_NORMEPS = 1e-8f;
constexpr float MARG      = 1.0f / 512.0f;   // a = b = 1/n

// ---------------------------------------------------------------------------
// init: alpha0 = 0, beta0 = 0, v = 1, cost[0..31] = 0  (ws/d_out are poisoned)
// ---------------------------------------------------------------------------
__global__ void init_k(float* __restrict__ a0, float* __restrict__ b0,
                       float* __restrict__ v, float* __restrict__ cost) {
    int i = blockIdx.x * 256 + threadIdx.x;   // grid 64x256 = 16384 = NB*NN
    a0[i] = 0.0f;
    b0[i] = 0.0f;
    v[i]  = 1.0f;
    if (i < NB) cost[i] = 0.0f;
}

// ---------------------------------------------------------------------------
// row norms of x and y: one wave per row (256 floats -> float4 per lane)
// ---------------------------------------------------------------------------
__global__ void norms_k(const float* __restrict__ x, const float* __restrict__ y,
                        float* __restrict__ nx, float* __restrict__ ny) {
    int w = threadIdx.x >> 6, lane = threadIdx.x & 63;
    int row = blockIdx.x * 4 + w;             // 0 .. 2*NB*NN-1  (8192 blocks)
    const float* base = (row < NB * NN) ? (x + (size_t)row * DD)
                                        : (y + (size_t)(row - NB * NN) * DD);
    float4 v4 = ((const float4*)base)[lane];
    float ss = v4.x * v4.x + v4.y * v4.y + v4.z * v4.z + v4.w * v4.w;
#pragma unroll
    for (int off = 32; off; off >>= 1) ss += __shfl_xor(ss, off);
    if (lane == 0) {
        float nv = sqrtf(ss);
        if (row < NB * NN) nx[row] = nv; else ny[row - NB * NN] = nv;
    }
}

// ---------------------------------------------------------------------------
// C[b,n,m] = 1 - <x_n,y_m>/max(|x_n||y_m|, 1e-8)
// 128x128 tile, BK=16, 256 threads, 8x8 micro-tile. fp32 vector FMA.
// grid = 32 batches * 16 tiles = 512 blocks
// ---------------------------------------------------------------------------
__global__ __launch_bounds__(256) void gemm_cos(
        const float* __restrict__ x, const float* __restrict__ y,
        const float* __restrict__ nx, const float* __restrict__ ny,
        float* __restrict__ C) {
    int blk = blockIdx.x;
    int b  = blk >> 4;
    int ti = (blk >> 2) & 3, tj = blk & 3;
    __shared__ float As[16][128];   // [k][row]
    __shared__ float Bs[16][128];   // [k][col]
    const float* xb = x + ((size_t)b * NN + ti * 128) * DD;
    const float* yb = y + ((size_t)b * NN + tj * 128) * DD;
    int tid = threadIdx.x;
    int ty = tid >> 4, tx = tid & 15;

    float acc[8][8];
#pragma unroll
    for (int i = 0; i < 8; ++i)
#pragma unroll
        for (int j = 0; j < 8; ++j) acc[i][j] = 0.0f;

    for (int k0 = 0; k0 < DD; k0 += 16) {
#pragma unroll
        for (int s = 0; s < 2; ++s) {
            int f = s * 256 + tid;          // 0..511
            int row = f >> 2;               // 0..127
            int kq  = (f & 3) << 2;         // 0,4,8,12
            float4 va = *(const float4*)(xb + (size_t)row * DD + k0 + kq);
            As[kq + 0][row] = va.x; As[kq + 1][row] = va.y;
            As[kq + 2][row] = va.z; As[kq + 3][row] = va.w;
            float4 vb = *(const float4*)(yb + (size_t)row * DD + k0 + kq);
            Bs[kq + 0][row] = vb.x; Bs[kq + 1][row] = vb.y;
            Bs[kq + 2][row] = vb.z; Bs[kq + 3][row] = vb.w;
        }
        __syncthreads();
#pragma unroll
        for (int kk = 0; kk < 16; ++kk) {
            float a[8], bb[8];
            *(float4*)&a[0]  = *(const float4*)&As[kk][ty * 8];
            *(float4*)&a[4]  = *(const float4*)&As[kk][ty * 8 + 4];
            *(float4*)&bb[0] = *(const float4*)&Bs[kk][tx * 8];
            *(float4*)&bb[4] = *(const float4*)&Bs[kk][tx * 8 + 4];
#pragma unroll
            for (int i = 0; i < 8; ++i)
#pragma unroll
                for (int j = 0; j < 8; ++j)
                    acc[i][j] = fmaf(a[i], bb[j], acc[i][j]);
        }
        __syncthreads();
    }

    int r0 = ti * 128 + ty * 8, c0 = tj * 128 + tx * 8;
    float nxr[8], nyc[8];
#pragma unroll
    for (int i = 0; i < 8; ++i) {
        nxr[i] = nx[b * NN + r0 + i];
        nyc[i] = ny[b * NN + c0 + i];
    }
    float* Cb = C + (size_t)b * NN * NN;
#pragma unroll
    for (int i = 0; i < 8; ++i) {
        float o[8];
#pragma unroll
        for (int j = 0; j < 8; ++j)
            o[j] = 1.0f - acc[i][j] / fmaxf(nxr[i] * nyc[j], F_NORMEPS);
        float4 w0 = make_float4(o[0], o[1], o[2], o[3]);
        float4 w1 = make_float4(o[4], o[5], o[6], o[7]);
        *(float4*)(Cb + (size_t)(r0 + i) * NN + c0)     = w0;
        *(float4*)(Cb + (size_t)(r0 + i) * NN + c0 + 4) = w1;
    }
}

// XCD-friendly block->batch map: 8 blocks of a batch share blk%8 (same XCD),
// 4 batches per XCD -> each batch's 1MB C slab stays in one XCD L2.
__device__ __forceinline__ void batch_oct(int blk, int& b, int& o) {
    int x8 = blk & 7, k = blk >> 3;   // k 0..31
    b = x8 * 4 + (k & 3);
    o = k >> 2;                       // 0..7 -> rows/cols [o*64, o*64+64)
}

// ---------------------------------------------------------------------------
// Phase U (iteration t): u_n = a / (sum_m exp((a_old_n + b_old_m - C_nm)/eps) * v_m + tiny)
// also writes alpha_new_n = alpha_old_n + eps*log(u_n)
// grid 256 x 256
// ---------------------------------------------------------------------------
__global__ __launch_bounds__(256) void sink_u(
        const float* __restrict__ C, const float* __restrict__ alpha_old,
        const float* __restrict__ beta_old, const float* __restrict__ v,
        float* __restrict__ u, float* __restrict__ alpha_new) {
    int b, o; batch_oct(blockIdx.x, b, o);
    __shared__ float sB[NN], sV[NN];
    for (int i = threadIdx.x; i < NN; i += 256) {
        sB[i] = beta_old[b * NN + i];
        sV[i] = v[b * NN + i];
    }
    __syncthreads();
    int w = threadIdx.x >> 6, lane = threadIdx.x & 63;
    const float* Cb = C + (size_t)b * NN * NN;
#pragma unroll 1
    for (int i = 0; i < 16; ++i) {
        int r = o * 64 + w * 16 + i;
        float al = alpha_old[b * NN + r];
        const float* Crow = Cb + (size_t)r * NN;
        float s = 0.0f;
#pragma unroll
        for (int j = 0; j < 8; ++j) {
            int m = lane + 64 * j;
            s += __expf((al + sB[m] - Crow[m]) * INV_EPS) * sV[m];
        }
#pragma unroll
        for (int off = 32; off; off >>= 1) s += __shfl_xor(s, off);
        if (lane == 0) {
            float uu = MARG / (s + F_TINY);
            u[b * NN + r] = uu;
            alpha_new[b * NN + r] = al + F_EPS * __logf(uu);
        }
    }
}

// ---------------------------------------------------------------------------
// Phase V (iteration t): v_m = b / (sum_n exp((a_old_n + b_old_m - C_nm)/eps) * u_n + tiny)
// (uses OLD alpha/beta and NEW u, exactly as the reference)
// also writes beta_new_m = beta_old_m + eps*log(v_m)
// grid 256 x 256
// ---------------------------------------------------------------------------
__global__ __launch_bounds__(256) void sink_v(
        const float* __restrict__ C, const float* __restrict__ alpha_old,
        const float* __restrict__ beta_old, const float* __restrict__ u,
        float* __restrict__ v, float* __restrict__ beta_new) {
    int b, o; batch_oct(blockIdx.x, b, o);
    __shared__ float sA[NN], sU[NN];
    __shared__ float sP[4][64];
    for (int i = threadIdx.x; i < NN; i += 256) {
        sA[i] = alpha_old[b * NN + i];
        sU[i] = u[b * NN + i];
    }
    __syncthreads();
    int c = o * 64 + (threadIdx.x & 63);
    int q = threadIdx.x >> 6;                 // n-quarter
    float be = beta_old[b * NN + c];
    const float* Cb = C + (size_t)b * NN * NN;
    float s = 0.0f;
    for (int n = q * 128; n < q * 128 + 128; ++n) {
        s += __expf((sA[n] + be - Cb[(size_t)n * NN + c]) * INV_EPS) * sU[n];
    }
    sP[q][threadIdx.x & 63] = s;
    __syncthreads();
    if (threadIdx.x < 64) {
        int cc = o * 64 + threadIdx.x;
        float tot = sP[0][threadIdx.x] + sP[1][threadIdx.x] +
                    sP[2][threadIdx.x] + sP[3][threadIdx.x];
        float vv = MARG / (tot + F_TINY);
        v[b * NN + cc] = vv;
        beta_new[b * NN + cc] = beta_old[b * NN + cc] + F_EPS * __logf(vv);
    }
}

// ---------------------------------------------------------------------------
// pi = exp((log u_n + alpha_n/eps) + (log v_m + beta_m/eps) - C/eps)
// cost_b = sum pi*C   (block partials -> atomicAdd; cost pre-zeroed by init_k)
// grid 512 x 256: block handles 32 rows of one batch
// ---------------------------------------------------------------------------
__global__ __launch_bounds__(256) void pi_cost(
        const float* __restrict__ C, const float* __restrict__ alpha,
        const float* __restrict__ beta, const float* __restrict__ u,
        const float* __restrict__ v, float* __restrict__ pi,
        float* __restrict__ cost) {
    int b = blockIdx.x >> 4, rg = blockIdx.x & 15;
    __shared__ float sQ[NN];
    __shared__ float sPart[4];
    for (int i = threadIdx.x; i < NN; i += 256)
        sQ[i] = __logf(v[b * NN + i]) + beta[b * NN + i] * INV_EPS;
    __syncthreads();
    int w = threadIdx.x >> 6, lane = threadIdx.x & 63;
    const float* Cb = C + (size_t)b * NN * NN;
    float* pib = pi + (size_t)b * NN * NN;
    float csum = 0.0f;
#pragma unroll 1
    for (int i = 0; i < 8; ++i) {
        int r = rg * 32 + w * 8 + i;
        float p = __logf(u[b * NN + r]) + alpha[b * NN + r] * INV_EPS;
        const float* Crow = Cb + (size_t)r * NN;
        float* prow = pib + (size_t)r * NN;
#pragma unroll
        for (int j = 0; j < 8; ++j) {
            int m = lane + 64 * j;
            float cv = Crow[m];
            float pv = __expf(p + sQ[m] - cv * INV_EPS);
            prow[m] = pv;
            csum += pv * cv;
        }
    }
#pragma unroll
    for (int off = 32; off; off >>= 1) csum += __shfl_xor(csum, off);
    if (lane == 0) sPart[w] = csum;
    __syncthreads();
    if (threadIdx.x == 0) {
        float tot = sPart[0] + sPart[1] + sPart[2] + sPart[3];
        atomicAdd(&cost[b], tot);
    }
}

// ---------------------------------------------------------------------------
extern "C" void kernel_launch(void* const* d_in, const int* in_sizes, int n_in,
                              void* d_out, int out_size, void* d_ws, size_t ws_size,
                              hipStream_t stream) {
    const float* x = (const float*)d_in[0];
    const float* y = (const float*)d_in[1];
    float* out  = (float*)d_out;
    float* cost = out;                                   // [32]
    float* pi   = out + 32;                              // [32*512*512]
    float* C    = out + 32 + (size_t)NB * NN * NN;       // [32*512*512]

    float* ws = (float*)d_ws;
    float* nx = ws;                   // 16384
    float* ny = ws + 16384;           // 16384
    float* alpha[2] = { ws + 32768, ws + 49152 };
    float* beta[2]  = { ws + 65536, ws + 81920 };
    float* u = ws + 98304;
    float* v = ws + 114688;

    init_k<<<dim3(64), dim3(256), 0, stream>>>(alpha[0], beta[0], v, cost);
    norms_k<<<dim3(8192), dim3(256), 0, stream>>>(x, y, nx, ny);
    gemm_cos<<<dim3(512), dim3(256), 0, stream>>>(x, y, nx, ny, C);

    for (int t = 1; t <= 15; ++t) {
        int ro = (t - 1) & 1, wo = t & 1;
        sink_u<<<dim3(256), dim3(256), 0, stream>>>(C, alpha[ro], beta[ro], v, u, alpha[wo]);
        sink_v<<<dim3(256), dim3(256), 0, stream>>>(C, alpha[ro], beta[ro], u, v, beta[wo]);
    }
    // 15 iterations (odd) -> final alpha/beta live in buffer 1
    pi_cost<<<dim3(512), dim3(256), 0, stream>>>(C, alpha[1], beta[1], u, v, pi, cost);
}